// Round 11
// baseline (69.285 us; speedup 1.0000x reference)
//
#include <hip/hip_runtime.h>
#include <math.h>
#include <string.h>

#define D 2048
#define NTOK 16384
#define NROW 11
#define MROWS_U32 (NROW * D / 2)   // 11264 uints = 44 KB (packed 2xf16)
#define K1_BLOCKS 1024
#define K1_THREADS 256             // 4 waves; 4 tokens/wave -> 16 tokens/block

// ws layout (4-byte units):
// [0..10] a_k   [16..26] b_k   [32] inv_temp  [33] alpha  [34..36] mix
// [40..63] M3 (8x3)  [64 .. 64+11264) packed-f16 W'  [WS_PART ..) partials [67][1024]
#define WS_A 0
#define WS_B 16
#define WS_IT 32
#define WS_ALPHA 33
#define WS_MIX 34
#define WS_M3 40
#define WS_MERGED 64
#define WS_PART (WS_MERGED + MROWS_U32)

// NOTE: must be __fp16 (not _Float16): clang's amdgcn builtins use V2h = v2__fp16
typedef __fp16 h2 __attribute__((ext_vector_type(2)));

__device__ __forceinline__ float wsum(float v){
#pragma unroll
  for (int m = 1; m < 64; m <<= 1) v += __shfl_xor(v, m, 64);
  return v;
}
__device__ __forceinline__ float wmax(float v){
#pragma unroll
  for (int m = 1; m < 64; m <<= 1) v = fmaxf(v, __shfl_xor(v, m, 64));
  return v;
}
__device__ __forceinline__ float rcp_fast(float x){ return __builtin_amdgcn_rcpf(x); }
__device__ __forceinline__ float tanh_fast(float x){
  float e = __expf(2.0f * x);
  return 1.0f - 2.0f * rcp_fast(e + 1.0f);
}
// uniform load -> SGPR
__device__ __forceinline__ float sload(const float* __restrict__ p){
  return __uint_as_float(__builtin_amdgcn_readfirstlane(__float_as_uint(*p)));
}
__device__ __forceinline__ h2 u2h(unsigned int u){ h2 h; memcpy(&h, &u, 4); return h; }
__device__ __forceinline__ unsigned int h2u(h2 h){ unsigned int u; memcpy(&u, &h, 4); return u; }

// dst = a.x*b.x + a.y*b.y + c  (f32 accumulate, v_dot2_f32_f16)
__device__ __forceinline__ float fdot2(h2 a, h2 b, float c){
#if __has_builtin(__builtin_amdgcn_fdot2)
  return __builtin_amdgcn_fdot2(a, b, c, false);
#else
  return fmaf((float)a[0], (float)b[0], fmaf((float)a[1], (float)b[1], c));
#endif
}

// ---------------- k0: merge rows (f16-packed) + constants (12 blocks) ----------------
__global__ __launch_bounds__(256) void k0_prep(
    const float* __restrict__ ln_w, const float* __restrict__ ln_b,
    const float* __restrict__ w_q2, const float* __restrict__ w_q3,
    const float* __restrict__ w_q6,
    const float* __restrict__ log_temp, const float* __restrict__ log_scale_mix,
    const float* __restrict__ q3_to_group, const float* __restrict__ log_wht_mix,
    float* __restrict__ ws)
{
  const int tid = threadIdx.x;
  const int k = blockIdx.x;
  unsigned int* wsu = (unsigned int*)ws;
  if (k < NROW){
    const float* row = (k < 2) ? (w_q2 + (size_t)k * D)
                     : (k < 5) ? (w_q3 + (size_t)(k - 2) * D)
                               : (w_q6 + (size_t)(k - 5) * D);
    float pa = 0.f, pb = 0.f;
    for (int i = tid * 2; i < D; i += 512){
      float w0 = row[i], w1 = row[i + 1];
      h2 h = __builtin_amdgcn_cvt_pkrtz(ln_w[i] * w0, ln_w[i + 1] * w1);
      // a_k accumulated from ROUNDED values (consistent with k1's dot)
      pa += (float)h[0] + (float)h[1];
      pb = fmaf(ln_b[i], w0, pb);
      pb = fmaf(ln_b[i + 1], w1, pb);
      wsu[WS_MERGED + k * 1024 + i / 2] = h2u(h);
    }
    __shared__ float red[8];
    pa = wsum(pa); pb = wsum(pb);
    if ((tid & 63) == 0){ red[tid >> 6] = pa; red[4 + (tid >> 6)] = pb; }
    __syncthreads();
    if (tid == 0){
      ws[WS_A + k] = red[0] + red[1] + red[2] + red[3];
      ws[WS_B + k] = red[4] + red[5] + red[6] + red[7];
    }
  } else if (tid == 0){
    float t = __expf(log_temp[0]);
    t = fminf(fmaxf(t, 0.1f), 5.0f);
    ws[WS_IT] = 1.0f / t;
    ws[WS_ALPHA] = 1.0f / (1.0f + __expf(-log_wht_mix[0]));
    float m0 = log_scale_mix[0], m1 = log_scale_mix[1], m2 = log_scale_mix[2];
    float mm = fmaxf(m0, fmaxf(m1, m2));
    float e0 = __expf(m0 - mm), e1 = __expf(m1 - mm), e2 = __expf(m2 - mm);
    float inv = 1.0f / (e0 + e1 + e2);
    ws[WS_MIX + 0] = e0 * inv; ws[WS_MIX + 1] = e1 * inv; ws[WS_MIX + 2] = e2 * inv;
    for (int r = 0; r < 8; ++r){
      float v0 = q3_to_group[r*3+0], v1 = q3_to_group[r*3+1], v2 = q3_to_group[r*3+2];
      float mx = fmaxf(v0, fmaxf(v1, v2));
      float f0 = __expf(v0 - mx), f1 = __expf(v1 - mx), f2 = __expf(v2 - mx);
      float iv = 1.0f / (f0 + f1 + f2);
      ws[WS_M3 + r*3 + 0] = f0 * iv;
      ws[WS_M3 + r*3 + 1] = f1 * iv;
      ws[WS_M3 + r*3 + 2] = f2 * iv;
    }
  }
}

// load one token row (8 x float4, 32B/lane pattern: lane owns 8 consecutive floats/chunk)
__device__ __forceinline__ void load_row(const float* __restrict__ p, float4* f){
#pragma unroll
  for (int c = 0; c < 4; ++c){
    f[2*c]     = *(const float4*)(p + c * 512);
    f[2*c + 1] = *(const float4*)(p + c * 512 + 4);
  }
}
// convert a loaded f32 row to packed f16 + accumulate sum/sq
__device__ __forceinline__ void cvt_row(const float4* __restrict__ f, h2* __restrict__ h,
                                        float& sum, float& sq){
#pragma unroll
  for (int i = 0; i < 8; ++i){
    float a0 = f[i].x, a1 = f[i].y, a2 = f[i].z, a3 = f[i].w;
    sum += (a0 + a1) + (a2 + a3);
    sq = fmaf(a0,a0, fmaf(a1,a1, fmaf(a2,a2, fmaf(a3,a3, sq))));
    h[2*i]   = __builtin_amdgcn_cvt_pkrtz(a0, a1);
    h[2*i+1] = __builtin_amdgcn_cvt_pkrtz(a2, a3);
  }
}

// dot rows [R0,R1) for a pair of tokens: ds_read_b128 + 8 fdot2 per chunk-row
template<int R0, int R1>
__device__ __forceinline__ void dot_rows(const unsigned int* __restrict__ sW,
                                         const h2* __restrict__ hx,
                                         const h2* __restrict__ hy,
                                         float* __restrict__ t0,
                                         float* __restrict__ t1, int lane){
#pragma unroll
  for (int c = 0; c < 4; ++c){
    const unsigned int* wb = sW + (c << 8) + lane * 4;
    const h2 x0 = hx[4*c], x1 = hx[4*c+1], x2 = hx[4*c+2], x3 = hx[4*c+3];
    const h2 y0 = hy[4*c], y1 = hy[4*c+1], y2 = hy[4*c+2], y3 = hy[4*c+3];
#pragma unroll
    for (int k = R0; k < R1; ++k){
      uint4 wq = *(const uint4*)(wb + (k << 10));
      h2 w0 = u2h(wq.x), w1 = u2h(wq.y), w2 = u2h(wq.z), w3 = u2h(wq.w);
      t0[k] = fdot2(x3, w3, fdot2(x2, w2, fdot2(x1, w1, fdot2(x0, w0, t0[k]))));
      t1[k] = fdot2(y3, w3, fdot2(y2, w2, fdot2(y1, w1, fdot2(y0, w0, t1[k]))));
    }
  }
}

// ---------------- k1: main per-token kernel ----------------
// 1024 blocks x 256 threads (4 waves), 4 tokens/wave (two pairs). Full 44 KB
// W' staged once per block (one barrier). Pair A's x loaded before staging;
// pair B's rows issued one-at-a-time under pair-A's dot/epilogue phases to
// cap transient VGPR (target <=128 for 16 waves/CU).
__global__ __launch_bounds__(256) void k1_main(
    const float* __restrict__ x, const float* __restrict__ ws,
    float* __restrict__ gout, float* __restrict__ hout, float* __restrict__ part)
{
  __shared__ unsigned int sW[MROWS_U32];  // 44 KB
  __shared__ float lred[4][68];
  const int tid  = threadIdx.x;
  const int lane = tid & 63;
  const int wid  = tid >> 6;
  const int blk  = blockIdx.x;
  const int tok0 = blk * 16 + wid * 4;

  const float* xp = x + (size_t)tok0 * D + lane * 8;

  // load pair A (tokens tok0, tok0+1) -- latency covered by staging + barrier
  float4 fA0[8], fA1[8];
  load_row(xp, fA0);
  load_row(xp + D, fA1);

  // stage full W' (2816 uint4 / 256 thr = 11 iters)
  {
    const uint4* src = (const uint4*)((const unsigned int*)ws + WS_MERGED);
    uint4* dst = (uint4*)sW;
#pragma unroll
    for (int i = 0; i < 11; ++i) dst[tid + i * 256] = src[tid + i * 256];
  }
  __syncthreads();

  // convert pair A
  float sA0 = 0.f, qA0 = 0.f, sA1 = 0.f, qA1 = 0.f;
  h2 hA0[16], hA1[16];
  cvt_row(fA0, hA0, sA0, qA0);
  cvt_row(fA1, hA1, sA1, qA1);

  // issue B token 1 (tok0+2)
  float4 fB0[8];
  load_row(xp + 2 * D, fB0);

  float tA0[NROW], tA1[NROW];
#pragma unroll
  for (int k = 0; k < NROW; ++k){ tA0[k] = 0.f; tA1[k] = 0.f; }

  // dot rows 0..5 for pair A (covers fB0 latency)
  dot_rows<0, 6>(sW, hA0, hA1, tA0, tA1, lane);

  // convert B1; issue B token 2 (tok0+3)
  float sB0 = 0.f, qB0 = 0.f;
  h2 hB0[16];
  cvt_row(fB0, hB0, sB0, qB0);
  float4 fB1[8];
  load_row(xp + 3 * D, fB1);

  // dot rows 6..10 for pair A (covers fB1 latency)
  dot_rows<6, NROW>(sW, hA0, hA1, tA0, tA1, lane);

  // reduce pair A
  sA0 = wsum(sA0); qA0 = wsum(qA0); sA1 = wsum(sA1); qA1 = wsum(qA1);
#pragma unroll
  for (int k = 0; k < NROW; ++k){ tA0[k] = wsum(tA0[k]); tA1[k] = wsum(tA1[k]); }

  // convert B2
  float sB1 = 0.f, qB1 = 0.f;
  h2 hB1[16];
  cvt_row(fB1, hB1, sB1, qB1);

  // uniform constants -> SGPRs
  float a[NROW], bb[NROW];
#pragma unroll
  for (int k = 0; k < NROW; ++k){ a[k] = sload(ws + WS_A + k); bb[k] = sload(ws + WS_B + k); }
  const float it    = sload(ws + WS_IT);
  const float alpha = sload(ws + WS_ALPHA);
  const float mix0 = sload(ws + WS_MIX), mix1 = sload(ws + WS_MIX + 1), mix2 = sload(ws + WS_MIX + 2);
  float M3r[8][3];
#pragma unroll
  for (int r = 0; r < 8; ++r){
#pragma unroll
    for (int g = 0; g < 3; ++g) M3r[r][g] = sload(ws + WS_M3 + r*3 + g);
  }

  // per-lane hexagram row constants
  float sgn[6];
#pragma unroll
  for (int j = 0; j < 6; ++j) sgn[j] = ((lane >> (5 - j)) & 1) ? 1.0f : -1.0f;
  const float C5 = 0.44721359549995793f; // 1/sqrt(5)
  const float A0c[6] = { C5,  C5,  C5,  C5,  C5, 0.f };
  const float A1c[6] = {-0.5f, 0.5f, -0.5f, 0.f, 0.f, 0.5f};
  const float A2c[6] = {-C5, -C5, 0.f, -C5, -C5, -C5};
  float cs0 = 0.f, cs1 = 0.f, cs2 = 0.f;
#pragma unroll
  for (int j = 0; j < 6; ++j){
    cs0 = fmaf(sgn[j], A0c[j], cs0);
    cs1 = fmaf(sgn[j], A1c[j], cs1);
    cs2 = fmaf(sgn[j], A2c[j], cs2);
  }
  const int pc = __popc(lane);
  const float w7c = 1.0f / 7.0f;
  float wh0 = (pc >= 5) ? w7c  : 0.f;
  float wh1 = (pc == 3) ? 0.05f: 0.f;
  float wh2 = (pc <= 1) ? w7c  : 0.f;
  const float m60 = (1.f - alpha)*cs0 + alpha*wh0;
  const float m61 = (1.f - alpha)*cs1 + alpha*wh1;
  const float m62 = (1.f - alpha)*cs2 + alpha*wh2;

  float hsum = 0.f, ga0 = 0.f, ga1 = 0.f, ga2 = 0.f;

  // -------- epilogue + second-pair dots interleaved --------
  // macro-free token epilogue, executed 4x with constant-indexed arrays
#define TOKEN_EPILOGUE(TOK, SUMJ, SQJ, TARR)                                         \
  {                                                                                  \
    const int tok = (TOK);                                                           \
    float mean = (SUMJ) * (1.0f / D);                                                \
    float var  = fmaf((SQJ), 1.0f / D, -mean * mean);                                \
    float rr   = rsqrtf(var + 1e-5f);                                                \
    float u[NROW];                                                                   \
    _Pragma("unroll")                                                                \
    for (int k = 0; k < NROW; ++k){                                                  \
      float d = fmaf(-mean, a[k], (TARR)[k]);                                        \
      u[k] = tanh_fast(fmaf(rr, d, bb[k]));                                          \
    }                                                                                \
    float p01 = u[0] + u[1], m01 = u[0] - u[1];                                      \
    float l0 = -p01*it, l1 = -m01*it, l2 = m01*it, l3 = p01*it;                      \
    float mx2 = fmaxf(fmaxf(l0, l1), fmaxf(l2, l3));                                 \
    float e0 = __expf(l0-mx2), e1 = __expf(l1-mx2), e2 = __expf(l2-mx2), e3 = __expf(l3-mx2); \
    float i2 = rcp_fast(e0 + e1 + e2 + e3);                                          \
    float s2g0 = e3 * i2, s2g1 = (e1 + e2) * i2, s2g2 = e0 * i2;                     \
    float l3v[8]; float mx3 = -1e30f;                                                \
    _Pragma("unroll")                                                                \
    for (int v = 0; v < 8; ++v){                                                     \
      float acc = ((v & 4) ? u[2] : -u[2]) + ((v & 2) ? u[3] : -u[3]) + ((v & 1) ? u[4] : -u[4]); \
      l3v[v] = acc * it;                                                             \
      mx3 = fmaxf(mx3, l3v[v]);                                                      \
    }                                                                                \
    float w3v[8]; float se3 = 0.f;                                                   \
    _Pragma("unroll")                                                                \
    for (int v = 0; v < 8; ++v){ w3v[v] = __expf(l3v[v] - mx3); se3 += w3v[v]; }     \
    float i3 = rcp_fast(se3);                                                        \
    float s3g0 = 0.f, s3g1 = 0.f, s3g2 = 0.f;                                        \
    _Pragma("unroll")                                                                \
    for (int v = 0; v < 8; ++v){                                                     \
      s3g0 = fmaf(w3v[v], M3r[v][0], s3g0);                                          \
      s3g1 = fmaf(w3v[v], M3r[v][1], s3g1);                                          \
      s3g2 = fmaf(w3v[v], M3r[v][2], s3g2);                                          \
    }                                                                                \
    s3g0 *= i3; s3g1 *= i3; s3g2 *= i3;                                              \
    float lg = 0.f;                                                                  \
    _Pragma("unroll")                                                                \
    for (int jj = 0; jj < 6; ++jj) lg = fmaf(sgn[jj], u[5 + jj], lg);                \
    lg *= it;                                                                        \
    float mx6 = wmax(lg);                                                            \
    float p   = __expf(lg - mx6);                                                    \
    float se6 = wsum(p);                                                             \
    float hw  = p * rcp_fast(se6);                                                   \
    hout[(size_t)tok * 64 + lane] = hw;                                              \
    hsum += hw;                                                                      \
    float s6g0 = wsum(hw * m60);                                                     \
    float s6g1 = wsum(hw * m61);                                                     \
    float s6g2 = wsum(hw * m62);                                                     \
    float g0 = mix0*s2g0 + mix1*s3g0 + mix2*s6g0;                                    \
    float g1 = mix0*s2g1 + mix1*s3g1 + mix2*s6g1;                                    \
    float g2 = mix0*s2g2 + mix1*s3g2 + mix2*s6g2;                                    \
    float gm = fmaxf(g0, fmaxf(g1, g2));                                             \
    float y0 = __expf(g0-gm), y1 = __expf(g1-gm), y2 = __expf(g2-gm);                \
    float gi = rcp_fast(y0 + y1 + y2);                                               \
    float gw0 = y0*gi, gw1 = y1*gi, gw2 = y2*gi;                                     \
    ga0 += gw0; ga1 += gw1; ga2 += gw2;                                              \
    if (lane < 3){                                                                   \
      float val = (lane == 0) ? gw0 : (lane == 1) ? gw1 : gw2;                       \
      gout[(size_t)tok * 3 + lane] = val;                                            \
    }                                                                                \
  }

  // epilogue pair A (covers nothing critical; B already loaded+converted)
  TOKEN_EPILOGUE(tok0 + 0, sA0, qA0, tA0)
  TOKEN_EPILOGUE(tok0 + 1, sA1, qA1, tA1)

  // dot pair B (W still staged; no extra barrier needed)
  float tB0[NROW], tB1[NROW];
#pragma unroll
  for (int k = 0; k < NROW; ++k){ tB0[k] = 0.f; tB1[k] = 0.f; }
  dot_rows<0, NROW>(sW, hB0, hB1, tB0, tB1, lane);

  sB0 = wsum(sB0); qB0 = wsum(qB0); sB1 = wsum(sB1); qB1 = wsum(qB1);
#pragma unroll
  for (int k = 0; k < NROW; ++k){ tB0[k] = wsum(tB0[k]); tB1[k] = wsum(tB1[k]); }

  TOKEN_EPILOGUE(tok0 + 2, sB0, qB0, tB0)
  TOKEN_EPILOGUE(tok0 + 3, sB1, qB1, tB1)
#undef TOKEN_EPILOGUE

  // block partials for lb_loss
  lred[wid][lane] = hsum;
  if (lane < 3){
    float val = (lane == 0) ? ga0 : (lane == 1) ? ga1 : ga2;
    lred[wid][64 + lane] = val;
  }
  __syncthreads();
  if (tid < 67){
    float v = lred[0][tid] + lred[1][tid] + lred[2][tid] + lred[3][tid];
    part[(size_t)tid * K1_BLOCKS + blk] = v;
  }
}

// ---------------- k2: final reduction + lb_loss ----------------
__global__ __launch_bounds__(1024) void k2_loss(const float* __restrict__ part,
                                                float* __restrict__ lout)
{
  __shared__ float sums[68];
  const int tid = threadIdx.x;
  const int lane = tid & 63;
  const int wid  = tid >> 6;
  for (int jv = wid; jv < 67; jv += 16){
    const float4* p = (const float4*)(part + (size_t)jv * K1_BLOCKS);
    float v = 0.f;
#pragma unroll
    for (int b = 0; b < K1_BLOCKS / 256; ++b){
      float4 q = p[lane + b * 64];
      v += (q.x + q.y) + (q.z + q.w);
    }
    v = wsum(v);
    if (lane == 0) sums[jv] = v;
  }
  __syncthreads();
  if (wid == 0){
    const float inv = 1.0f / (float)NTOK;
    float mh = sums[lane] * inv;
    float term = 0.1f * mh * logf(mh + 1e-8f);
    if (lane < 3){
      float mg = sums[64 + lane] * inv;
      term += mg * logf(mg + 1e-8f);
    }
    float L = wsum(term);
    if (lane == 0) lout[0] = L;
  }
}

extern "C" void kernel_launch(void* const* d_in, const int* in_sizes, int n_in,
                              void* d_out, int out_size, void* d_ws, size_t ws_size,
                              hipStream_t stream)
{
  const float* x             = (const float*)d_in[0];
  const float* ln_w          = (const float*)d_in[1];
  const float* ln_b          = (const float*)d_in[2];
  const float* w_q2          = (const float*)d_in[3];
  const float* w_q3          = (const float*)d_in[4];
  const float* w_q6          = (const float*)d_in[5];
  const float* log_temp      = (const float*)d_in[6];
  const float* log_scale_mix = (const float*)d_in[7];
  const float* q3_to_group   = (const float*)d_in[8];
  const float* log_wht_mix   = (const float*)d_in[9];

  float* out  = (float*)d_out;
  float* gout = out;                                        // (B,T,3)
  float* hout = out + (size_t)NTOK * 3;                     // (B,T,64)
  float* lout = out + (size_t)NTOK * 3 + (size_t)NTOK * 64; // scalar
  float* ws   = (float*)d_ws;

  k0_prep<<<12, 256, 0, stream>>>(ln_w, ln_b, w_q2, w_q3, w_q6,
                                  log_temp, log_scale_mix, q3_to_group, log_wht_mix, ws);
  k1_main<<<K1_BLOCKS, K1_THREADS, 0, stream>>>(x, ws, gout, hout, ws + WS_PART);
  k2_loss<<<1, 1024, 0, stream>>>(ws + WS_PART, lout);
}